// Round 7
// baseline (26.282 us; speedup 1.0000x reference)
//
#include <hip/hip_runtime.h>

// CantileverPINN: loss = mean((d4/dx4 w(x) - 1)^2), w = MLP 1->15->30->60->1 tanh.
// w_xxxx(x) is analytic on [0,1]: exact fp32 4th-order jets at 64 Chebyshev
// nodes, DCT -> coefficients, degree-63 Clenshaw per point. TWO kernels:
//  K1: 64 nodes, wave-per-node (16 blocks x 256); block 0 zeros acc+counter
//  K2: per-block DCT (spread over 256 lanes) + Clenshaw (2 pts/thread) +
//      block reduce + ONE relaxed u64 fixed-point atomicAdd per block;
//      last block (relaxed counter) converts and writes out.
// No acquire/release fences anywhere (R5 showed agent-scope ACQ_REL costs
// ~27 us via per-block L2 writeback/invalidate on 8-XCD gfx950).
// Determinism: integer fixed-point adds are order-invariant; block-internal
// reduction is a fixed shuffle tree.

#define M_NODES 64
#define FP_SCALE 1073741824.0   // 2^30

typedef unsigned long long u64;

__device__ __forceinline__ float cos_turns(float phi) {   // cos(2*pi*phi)
    float r;
    asm("v_cos_f32 %0, %1" : "=v"(r) : "v"(phi));
    return r;
}

__device__ __forceinline__ float fast_tanh(float u) {
    float e = __expf(2.0f * u);
    return 1.0f - 2.0f / (e + 1.0f);   // e=inf -> 1, e=0 -> -1
}

struct TanhD { float t, s, p2, p3, p4; };

__device__ __forceinline__ TanhD tanh_derivs(float u0) {
    TanhD d;
    float t = fast_tanh(u0);
    float s = fmaf(-t, t, 1.0f);
    float ts = t * s;
    float t2 = t * t;
    d.t = t;
    d.s = s;
    d.p2 = -2.0f * ts;
    d.p3 = s * fmaf(4.0f, t2, -2.0f * s);          // s(4t^2 - 2s)
    d.p4 = 8.0f * ts * fmaf(-1.0f, t2, 2.0f * s);  // 8ts(2s - t^2)
    return d;
}

__device__ __forceinline__ void tanh_jet(const float u[5], float f[5]) {
    TanhD d = tanh_derivs(u[0]);
    float u1 = u[1], u2 = u[2], u3 = u[3], u4 = u[4];
    float u1sq = u1 * u1;
    f[0] = d.t;
    f[1] = d.s * u1;
    f[2] = fmaf(d.p2, u1sq, d.s * u2);
    f[3] = fmaf(d.p3, u1sq * u1, fmaf(3.0f * d.p2, u1 * u2, d.s * u3));
    f[4] = fmaf(d.p4, u1sq * u1sq,
           fmaf(6.0f * d.p3, u1sq * u2,
           fmaf(3.0f * d.p2, u2 * u2,
           fmaf(4.0f * d.p2, u1 * u3, d.s * u4))));
}

__device__ __forceinline__ float tanh_jet_d4(float u0, float u1, float u2,
                                             float u3, float u4) {
    TanhD d = tanh_derivs(u0);
    const float u1sq = u1 * u1;
    return fmaf(d.p4, u1sq * u1sq,
           fmaf(6.0f * d.p3, u1sq * u2,
           fmaf(3.0f * d.p2, u2 * u2,
           fmaf(4.0f * d.p2, u1 * u3, d.s * u4))));
}

// ---- K1: w_xxxx at 64 Chebyshev nodes, one wave per node. 16 blocks x 256. ----
__global__ __launch_bounds__(256, 1)
void pinn_node_kernel(const float* __restrict__ W1, const float* __restrict__ b1,
                      const float* __restrict__ W2, const float* __restrict__ b2,
                      const float* __restrict__ W3, const float* __restrict__ b3,
                      const float* __restrict__ W4,
                      float* __restrict__ f_nodes,
                      u64* __restrict__ acc, unsigned int* __restrict__ counter) {
    __shared__ float sW1[15], sB1[15], sB2[30], sB3[60], sW4[60];
    __shared__ float sW2[15 * 30];    // [i][j], lane j reads stride-1
    __shared__ float sW3[30 * 60];    // [i][m], lane m reads stride-1
    __shared__ float gj[4][15][5];    // L1 jets per node
    __shared__ float h2[4][30][5];    // h2 jets per node

    const int t = threadIdx.x;
    if (blockIdx.x == 0 && t == 0) { *acc = 0ull; *counter = 0u; }

    for (int idx = t; idx < 450; idx += 256) sW2[idx] = W2[idx];
    for (int idx = t; idx < 1800; idx += 256) sW3[idx] = W3[idx];
    if (t < 15) { sW1[t] = W1[t]; sB1[t] = b1[t]; }
    if (t < 30) sB2[t] = b2[t];
    if (t < 60) { sB3[t] = b3[t]; sW4[t] = W4[t]; }
    __syncthreads();

    const int nd   = t >> 6;                      // node within block (0..3)
    const int lane = t & 63;
    const int node = blockIdx.x * 4 + nd;         // 0..63

    // x = 0.5 + 0.5*cos(pi*(node+0.5)/64); turns = (2*node+1)/256 exact
    const float phi = (float)(2 * node + 1) * (1.0f / 256.0f);
    const float xi  = fmaf(0.5f, cos_turns(phi), 0.5f);

    // phase 0: lanes 0..14 compute L1 jets
    if (lane < 15) {
        const float w = sW1[lane];
        TanhD d = tanh_derivs(fmaf(w, xi, sB1[lane]));
        const float w2 = w * w;
        gj[nd][lane][0] = d.t;
        gj[nd][lane][1] = d.s * w;
        gj[nd][lane][2] = d.p2 * w2;
        gj[nd][lane][3] = d.p3 * w2 * w;
        gj[nd][lane][4] = d.p4 * w2 * w2;
    }
    __syncthreads();

    // phase A: lanes 0..29 compute h2 jets (broadcast gj, stride-1 W2)
    if (lane < 30) {
        float z[5] = { sB2[lane], 0.0f, 0.0f, 0.0f, 0.0f };
        for (int i = 0; i < 15; ++i) {
            const float wij = sW2[i * 30 + lane];
            #pragma unroll
            for (int k = 0; k < 5; ++k) z[k] = fmaf(wij, gj[nd][i][k], z[k]);
        }
        float h[5];
        tanh_jet(z, h);
        #pragma unroll
        for (int k = 0; k < 5; ++k) h2[nd][lane][k] = h[k];
    }
    __syncthreads();

    // phase B: lanes 0..59 compute z3 jets, d4, dot with W4
    float v = 0.0f;
    if (lane < 60) {
        float z[5] = { sB3[lane], 0.0f, 0.0f, 0.0f, 0.0f };
        for (int i = 0; i < 30; ++i) {
            const float wim = sW3[i * 60 + lane];
            #pragma unroll
            for (int k = 0; k < 5; ++k) z[k] = fmaf(wim, h2[nd][i][k], z[k]);
        }
        v = sW4[lane] * tanh_jet_d4(z[0], z[1], z[2], z[3], z[4]);
    }
    #pragma unroll
    for (int off = 32; off > 0; off >>= 1) v += __shfl_down(v, off, 64);
    if (lane == 0) f_nodes[node] = v;
}

// ---- K2: DCT + Clenshaw (2 pts/thread) + block reduce + atomic tail ----
__global__ __launch_bounds__(256, 4)
void pinn_eval_kernel(const float* __restrict__ x,
                      const float* __restrict__ f_nodes,
                      u64* __restrict__ acc, unsigned int* __restrict__ counter,
                      float* __restrict__ out, int n, double inv_n_scale) {
    __shared__ float sf[M_NODES];
    __shared__ float sdct[4][M_NODES];
    __shared__ float sc[M_NODES];
    __shared__ float wsum[4];

    const int t = threadIdx.x;
    const int gid = blockIdx.x * 256 + t;

    // issue the x load early (float2 = 2 points per thread)
    float2 xv = make_float2(0.0f, 0.0f);
    if (2 * gid + 1 < n) xv = ((const float2*)x)[gid];

    if (t < M_NODES) sf[t] = f_nodes[t];
    __syncthreads();

    // DCT-II spread across all 256 threads: k = t&63, 16 j's per thread
    {
        const int k = t & 63;
        const int part = t >> 6;
        const int j0 = part * 16;
        float s = 0.0f;
        for (int j = j0; j < j0 + 16; ++j) {
            // cos(pi*k*(j+0.5)/64) = cos(2*pi*(k*(2j+1) mod 256)/256), exact
            const int num = (k * (2 * j + 1)) & 255;
            s = fmaf(sf[j], cos_turns((float)num * (1.0f / 256.0f)), s);
        }
        sdct[part][k] = s;
    }
    __syncthreads();
    if (t < M_NODES) {
        const float s = sdct[0][t] + sdct[1][t] + sdct[2][t] + sdct[3][t];
        sc[t] = s * ((t == 0) ? (1.0f / 64.0f) : (2.0f / 64.0f));
    }
    __syncthreads();

    // Clenshaw, degree 63, two independent chains (ILP)
    const float ta = fmaf(2.0f, xv.x, -1.0f);
    const float tb = fmaf(2.0f, xv.y, -1.0f);
    const float ta2 = ta + ta, tb2 = tb + tb;
    float a1 = 0.0f, a2 = 0.0f, b1 = 0.0f, b2 = 0.0f;
    #pragma unroll 4
    for (int k = M_NODES - 1; k >= 1; --k) {
        const float ck = sc[k];
        const float an = fmaf(ta2, a1, ck - a2);
        const float bn = fmaf(tb2, b1, ck - b2);
        a2 = a1; a1 = an;
        b2 = b1; b1 = bn;
    }
    const float fa = fmaf(ta, a1, sc[0] - a2);     // w_xxxx(x0)
    const float fb = fmaf(tb, b1, sc[0] - b2);     // w_xxxx(x1)

    const float ra = fa - 1.0f, rb = fb - 1.0f;    // P/(E*I) = 1
    float val = 0.0f;
    if (2 * gid < n)     val += ra * ra;
    if (2 * gid + 1 < n) val += rb * rb;

    #pragma unroll
    for (int off = 32; off > 0; off >>= 1) val += __shfl_down(val, off, 64);
    if ((t & 63) == 0) wsum[t >> 6] = val;
    __syncthreads();

    if (t == 0) {
        const float bsum = wsum[0] + wsum[1] + wsum[2] + wsum[3];
        const u64 inc = (u64)((double)bsum * FP_SCALE);   // exact, deterministic
        u64 old = atomicAdd(acc, inc);                    // relaxed, no fence
        // materialize 'old' -> s_waitcnt vmcnt(0): our acc-add is committed
        // at the coherence point before the counter increment is issued.
        asm volatile("" :: "v"(old) : "memory");
        const unsigned int cnt = atomicAdd(counter, 1u);  // relaxed
        if (cnt == gridDim.x - 1) {
            const u64 total = atomicAdd(acc, 0ull);       // coherent read
            out[0] = (float)((double)total * inv_n_scale);
        }
    }
}

extern "C" void kernel_launch(void* const* d_in, const int* in_sizes, int n_in,
                              void* d_out, int out_size, void* d_ws, size_t ws_size,
                              hipStream_t stream) {
    const float* x  = (const float*)d_in[0];
    const float* W1 = (const float*)d_in[1];
    const float* b1 = (const float*)d_in[2];
    const float* W2 = (const float*)d_in[3];
    const float* b2 = (const float*)d_in[4];
    const float* W3 = (const float*)d_in[5];
    const float* b3 = (const float*)d_in[6];
    const float* W4 = (const float*)d_in[7];
    // d_in[8] = b4: constant offset; vanishes under d^4/dx^4.

    const int n = in_sizes[0];
    const int npairs = (n + 1) / 2;
    const int nblocks = (npairs + 255) / 256;       // 512 for n=262144

    float* ws       = (float*)d_ws;
    float* f_nodes  = ws;                           // 64 floats
    u64*   acc      = (u64*)(ws + M_NODES);         // byte 256, 8B-aligned
    unsigned int* counter = (unsigned int*)(ws + M_NODES + 2);

    const double inv_n_scale = 1.0 / (FP_SCALE * (double)n);

    pinn_node_kernel<<<16, 256, 0, stream>>>(W1, b1, W2, b2, W3, b3, W4,
                                             f_nodes, acc, counter);
    pinn_eval_kernel<<<nblocks, 256, 0, stream>>>(x, f_nodes, acc, counter,
                                                  (float*)d_out, n, inv_n_scale);
}

// Round 8
// 15.645 us; speedup vs baseline: 1.6799x; 1.6799x over previous
//
#include <hip/hip_runtime.h>

// CantileverPINN: loss = mean((d4/dx4 w(x) - 1)^2), w = MLP 1->15->30->60->1 tanh.
// w_xxxx(x) is analytic on [0,1]: exact fp32 4th-order jets at 64 Chebyshev
// nodes, then degree-63 Chebyshev eval (Clenshaw). THREE kernels, NO atomics
// (R5/R7 showed any device-scope atomic/fence costs ~8-27 us on 8-XCD gfx950;
// kernel boundaries are cheaper):
//  K1: 64 nodes, wave-per-node (16 blocks x 256)
//  K2: per-block DCT (spread over 256 lanes, ~16 cos each) + Clenshaw
//      (2 pts/thread, dual chains for ILP) + block reduce -> partials
//  K3: final reduce (1 block) -> out

#define M_NODES 64

__device__ __forceinline__ float cos_turns(float phi) {   // cos(2*pi*phi)
    float r;
    asm("v_cos_f32 %0, %1" : "=v"(r) : "v"(phi));
    return r;
}

__device__ __forceinline__ float fast_tanh(float u) {
    float e = __expf(2.0f * u);
    return 1.0f - 2.0f / (e + 1.0f);   // e=inf -> 1, e=0 -> -1
}

struct TanhD { float t, s, p2, p3, p4; };

__device__ __forceinline__ TanhD tanh_derivs(float u0) {
    TanhD d;
    float t = fast_tanh(u0);
    float s = fmaf(-t, t, 1.0f);
    float ts = t * s;
    float t2 = t * t;
    d.t = t;
    d.s = s;
    d.p2 = -2.0f * ts;
    d.p3 = s * fmaf(4.0f, t2, -2.0f * s);          // s(4t^2 - 2s)
    d.p4 = 8.0f * ts * fmaf(-1.0f, t2, 2.0f * s);  // 8ts(2s - t^2)
    return d;
}

__device__ __forceinline__ void tanh_jet(const float u[5], float f[5]) {
    TanhD d = tanh_derivs(u[0]);
    float u1 = u[1], u2 = u[2], u3 = u[3], u4 = u[4];
    float u1sq = u1 * u1;
    f[0] = d.t;
    f[1] = d.s * u1;
    f[2] = fmaf(d.p2, u1sq, d.s * u2);
    f[3] = fmaf(d.p3, u1sq * u1, fmaf(3.0f * d.p2, u1 * u2, d.s * u3));
    f[4] = fmaf(d.p4, u1sq * u1sq,
           fmaf(6.0f * d.p3, u1sq * u2,
           fmaf(3.0f * d.p2, u2 * u2,
           fmaf(4.0f * d.p2, u1 * u3, d.s * u4))));
}

__device__ __forceinline__ float tanh_jet_d4(float u0, float u1, float u2,
                                             float u3, float u4) {
    TanhD d = tanh_derivs(u0);
    const float u1sq = u1 * u1;
    return fmaf(d.p4, u1sq * u1sq,
           fmaf(6.0f * d.p3, u1sq * u2,
           fmaf(3.0f * d.p2, u2 * u2,
           fmaf(4.0f * d.p2, u1 * u3, d.s * u4))));
}

// ---- K1: w_xxxx at 64 Chebyshev nodes, one wave per node. 16 blocks x 256. ----
__global__ __launch_bounds__(256, 1)
void pinn_node_kernel(const float* __restrict__ W1, const float* __restrict__ b1,
                      const float* __restrict__ W2, const float* __restrict__ b2,
                      const float* __restrict__ W3, const float* __restrict__ b3,
                      const float* __restrict__ W4,
                      float* __restrict__ f_nodes) {
    __shared__ float sW1[15], sB1[15], sB2[30], sB3[60], sW4[60];
    __shared__ float sW2[15 * 30];    // [i][j], lane j reads stride-1
    __shared__ float sW3[30 * 60];    // [i][m], lane m reads stride-1
    __shared__ float gj[4][15][5];    // L1 jets per node
    __shared__ float h2[4][30][5];    // h2 jets per node

    const int t = threadIdx.x;
    for (int idx = t; idx < 450; idx += 256) sW2[idx] = W2[idx];
    for (int idx = t; idx < 1800; idx += 256) sW3[idx] = W3[idx];
    if (t < 15) { sW1[t] = W1[t]; sB1[t] = b1[t]; }
    if (t < 30) sB2[t] = b2[t];
    if (t < 60) { sB3[t] = b3[t]; sW4[t] = W4[t]; }
    __syncthreads();

    const int nd   = t >> 6;                      // node within block (0..3)
    const int lane = t & 63;
    const int node = blockIdx.x * 4 + nd;         // 0..63

    // x = 0.5 + 0.5*cos(pi*(node+0.5)/64); turns = (2*node+1)/256 exact
    const float phi = (float)(2 * node + 1) * (1.0f / 256.0f);
    const float xi  = fmaf(0.5f, cos_turns(phi), 0.5f);

    // phase 0: lanes 0..14 compute L1 jets
    if (lane < 15) {
        const float w = sW1[lane];
        TanhD d = tanh_derivs(fmaf(w, xi, sB1[lane]));
        const float w2 = w * w;
        gj[nd][lane][0] = d.t;
        gj[nd][lane][1] = d.s * w;
        gj[nd][lane][2] = d.p2 * w2;
        gj[nd][lane][3] = d.p3 * w2 * w;
        gj[nd][lane][4] = d.p4 * w2 * w2;
    }
    __syncthreads();

    // phase A: lanes 0..29 compute h2 jets (broadcast gj, stride-1 W2)
    if (lane < 30) {
        float z[5] = { sB2[lane], 0.0f, 0.0f, 0.0f, 0.0f };
        for (int i = 0; i < 15; ++i) {
            const float wij = sW2[i * 30 + lane];
            #pragma unroll
            for (int k = 0; k < 5; ++k) z[k] = fmaf(wij, gj[nd][i][k], z[k]);
        }
        float h[5];
        tanh_jet(z, h);
        #pragma unroll
        for (int k = 0; k < 5; ++k) h2[nd][lane][k] = h[k];
    }
    __syncthreads();

    // phase B: lanes 0..59 compute z3 jets, d4, dot with W4
    float v = 0.0f;
    if (lane < 60) {
        float z[5] = { sB3[lane], 0.0f, 0.0f, 0.0f, 0.0f };
        for (int i = 0; i < 30; ++i) {
            const float wim = sW3[i * 60 + lane];
            #pragma unroll
            for (int k = 0; k < 5; ++k) z[k] = fmaf(wim, h2[nd][i][k], z[k]);
        }
        v = sW4[lane] * tanh_jet_d4(z[0], z[1], z[2], z[3], z[4]);
    }
    #pragma unroll
    for (int off = 32; off > 0; off >>= 1) v += __shfl_down(v, off, 64);
    if (lane == 0) f_nodes[node] = v;
}

// ---- K2: per-block DCT + Clenshaw (2 pts/thread) + block reduce -> partials ----
__global__ __launch_bounds__(256, 4)
void pinn_eval_kernel(const float* __restrict__ x,
                      const float* __restrict__ f_nodes,
                      float* __restrict__ partials, int n) {
    __shared__ float sf[M_NODES];
    __shared__ float sdct[4][M_NODES];
    __shared__ float sc[M_NODES];
    __shared__ float wsum[4];

    const int t = threadIdx.x;
    const int gid = blockIdx.x * 256 + t;
    const int i0 = 2 * gid;

    // issue the x load early (float2 = 2 points per thread)
    float2 xv = make_float2(0.0f, 0.0f);
    if (i0 + 1 < n)      xv = ((const float2*)x)[gid];
    else if (i0 < n)     xv.x = x[i0];

    if (t < M_NODES) sf[t] = f_nodes[t];
    __syncthreads();

    // DCT-II spread across all 256 threads: k = t&63, 16 j's per thread
    {
        const int k = t & 63;
        const int part = t >> 6;
        const int j0 = part * 16;
        float s = 0.0f;
        for (int j = j0; j < j0 + 16; ++j) {
            // cos(pi*k*(j+0.5)/64) = cos(2*pi*(k*(2j+1) mod 256)/256), exact
            const int num = (k * (2 * j + 1)) & 255;
            s = fmaf(sf[j], cos_turns((float)num * (1.0f / 256.0f)), s);
        }
        sdct[part][k] = s;
    }
    __syncthreads();
    if (t < M_NODES) {
        const float s = sdct[0][t] + sdct[1][t] + sdct[2][t] + sdct[3][t];
        sc[t] = s * ((t == 0) ? (1.0f / 64.0f) : (2.0f / 64.0f));
    }
    __syncthreads();

    // Clenshaw, degree 63, two independent chains (ILP)
    const float ta = fmaf(2.0f, xv.x, -1.0f);
    const float tb = fmaf(2.0f, xv.y, -1.0f);
    const float ta2 = ta + ta, tb2 = tb + tb;
    float a1 = 0.0f, a2 = 0.0f, b1 = 0.0f, b2 = 0.0f;
    #pragma unroll 4
    for (int k = M_NODES - 1; k >= 1; --k) {
        const float ck = sc[k];
        const float an = fmaf(ta2, a1, ck - a2);
        const float bn = fmaf(tb2, b1, ck - b2);
        a2 = a1; a1 = an;
        b2 = b1; b1 = bn;
    }
    const float fa = fmaf(ta, a1, sc[0] - a2);     // w_xxxx(x0)
    const float fb = fmaf(tb, b1, sc[0] - b2);     // w_xxxx(x1)

    const float ra = fa - 1.0f, rb = fb - 1.0f;    // P/(E*I) = 1
    float val = 0.0f;
    if (i0 < n)     val += ra * ra;
    if (i0 + 1 < n) val += rb * rb;

    #pragma unroll
    for (int off = 32; off > 0; off >>= 1) val += __shfl_down(val, off, 64);
    if ((t & 63) == 0) wsum[t >> 6] = val;
    __syncthreads();
    if (t == 0) partials[blockIdx.x] = wsum[0] + wsum[1] + wsum[2] + wsum[3];
}

// ---- K3: final reduce ----
__global__ __launch_bounds__(256)
void pinn_reduce_kernel(const float* __restrict__ partials, int nblocks,
                        float* __restrict__ out, float scale) {
    __shared__ float ws[4];
    const int t = threadIdx.x;
    float v = 0.0f;
    for (int i = t; i < nblocks; i += 256) v += partials[i];
    #pragma unroll
    for (int off = 32; off > 0; off >>= 1) v += __shfl_down(v, off, 64);
    if ((t & 63) == 0) ws[t >> 6] = v;
    __syncthreads();
    if (t == 0) out[0] = (ws[0] + ws[1] + ws[2] + ws[3]) * scale;
}

extern "C" void kernel_launch(void* const* d_in, const int* in_sizes, int n_in,
                              void* d_out, int out_size, void* d_ws, size_t ws_size,
                              hipStream_t stream) {
    const float* x  = (const float*)d_in[0];
    const float* W1 = (const float*)d_in[1];
    const float* b1 = (const float*)d_in[2];
    const float* W2 = (const float*)d_in[3];
    const float* b2 = (const float*)d_in[4];
    const float* W3 = (const float*)d_in[5];
    const float* b3 = (const float*)d_in[6];
    const float* W4 = (const float*)d_in[7];
    // d_in[8] = b4: constant offset; vanishes under d^4/dx^4.

    const int n = in_sizes[0];
    const int npairs = (n + 1) / 2;
    const int nblocks = (npairs + 255) / 256;       // 512 for n=262144

    float* ws       = (float*)d_ws;
    float* f_nodes  = ws;                 // 64 floats
    float* partials = ws + M_NODES;       // nblocks floats

    pinn_node_kernel<<<16, 256, 0, stream>>>(W1, b1, W2, b2, W3, b3, W4, f_nodes);
    pinn_eval_kernel<<<nblocks, 256, 0, stream>>>(x, f_nodes, partials, n);
    pinn_reduce_kernel<<<1, 256, 0, stream>>>(partials, nblocks, (float*)d_out,
                                              1.0f / (float)n);
}